// Round 12
// baseline (126.706 us; speedup 1.0000x reference)
//
#include <hip/hip_runtime.h>
#include <hip/hip_bf16.h>

typedef __bf16 bf16;
typedef __attribute__((ext_vector_type(8))) __bf16 bf16x8;
typedef __attribute__((ext_vector_type(4))) __bf16 bf16x4;
typedef __attribute__((ext_vector_type(4))) float f32x4;
typedef __attribute__((ext_vector_type(16))) float f32x16;
typedef unsigned int uint;

#define MFMA16(a, b, c) __builtin_amdgcn_mfma_f32_16x16x32_bf16(a, b, c, 0, 0, 0)
#define MFMA32(a, b, c) __builtin_amdgcn_mfma_f32_32x32x16_bf16(a, b, c, 0, 0, 0)

#define GLOAD_LDS(gp, lp) \
  __builtin_amdgcn_global_load_lds( \
      (const __attribute__((address_space(1))) void*)(gp), \
      (__attribute__((address_space(3))) void*)(lp), 16, 0, 0)

#define QSCALE 0.18033688011112042f  /* 0.125 * log2(e) */

__device__ __forceinline__ uint pack2(float a, float b) {
  unsigned short x = __builtin_bit_cast(unsigned short, (bf16)a);
  unsigned short y = __builtin_bit_cast(unsigned short, (bf16)b);
  return (uint)x | ((uint)y << 16);
}

// ---------------- prep: x cvt (blocks 0..2047) + 4 weight transposes ----------
__global__ __launch_bounds__(256) void prep_kernel(
    const float* __restrict__ x, bf16* __restrict__ y,
    const float* __restrict__ W0, const float* __restrict__ W1,
    const float* __restrict__ W2, const float* __restrict__ W3,
    bf16* __restrict__ T0, bf16* __restrict__ T1,
    bf16* __restrict__ T2, bf16* __restrict__ T3) {
  const int bid = blockIdx.x;
  if (bid < 2048) {
    int i = (bid * 256 + threadIdx.x) * 8;
    float4 a = *(const float4*)(x + i);
    float4 b = *(const float4*)(x + i + 4);
    bf16x8 v;
    v[0] = (bf16)a.x; v[1] = (bf16)a.y; v[2] = (bf16)a.z; v[3] = (bf16)a.w;
    v[4] = (bf16)b.x; v[5] = (bf16)b.y; v[6] = (bf16)b.z; v[7] = (bf16)b.w;
    *(bf16x8*)(y + i) = v;
    return;
  }
  const int wq = bid - 2048;
  const int z = wq >> 10, rem = wq & 1023;
  const float* W; bf16* T;
  switch (z) {
    case 0: W = W0; T = T0; break;
    case 1: W = W1; T = T1; break;
    case 2: W = W2; T = T2; break;
    default: W = W3; T = T3; break;
  }
  const float scl = (z == 0) ? QSCALE : 1.0f;
  __shared__ float tile[32][33];
  int tx = threadIdx.x & 31;
  int ty = threadIdx.x >> 5;
  int bx = (rem & 31) * 32, by = (rem >> 5) * 32;
#pragma unroll
  for (int i = 0; i < 32; i += 8)
    tile[ty + i][tx] = W[(size_t)(by + ty + i) * 1024 + bx + tx];
  __syncthreads();
#pragma unroll
  for (int i = 0; i < 32; i += 8)
    T[(size_t)(bx + ty + i) * 1024 + by + tx] = (bf16)(tile[tx][ty + i] * scl);
}

// ---------------- fused QKV GEMM: [4096][1024] x [3072][1024]^T ----------------
__global__ __launch_bounds__(256, 2) void gemm_qkv_kernel(
    const bf16* __restrict__ A, const bf16* __restrict__ Bt,
    const float* __restrict__ b0, const float* __restrict__ b1,
    const float* __restrict__ b2, bf16* __restrict__ o0,
    bf16* __restrict__ o1, bf16* __restrict__ o2) {
  __shared__ bf16 As[128 * 64];
  __shared__ bf16 Bs[128 * 64];
  const int f = blockIdx.y * 24 + blockIdx.x;
  const int wg = (f % 8) * 96 + f / 8;
  const int bn = wg % 24, bm = wg / 24;
  const int t = threadIdx.x;
  const int lane = t & 63, wid = t >> 6;
  const int wy = wid >> 1, wx = wid & 1;
  const int lr = lane & 15, lg = lane >> 4;
  const bf16* Arow = A + (size_t)bm * 128 * 1024;
  const bf16* Brow = Bt + (size_t)bn * 128 * 1024;
  f32x4 acc[4][4] = {};

  for (int k0 = 0; k0 < 1024; k0 += 64) {
    __syncthreads();
#pragma unroll
    for (int i = 0; i < 4; i++) {
      int off = i * 256 + t;
      int row = off >> 3, ch = off & 7;
      int gch = ch ^ (row & 7);
      GLOAD_LDS(Arow + (size_t)row * 1024 + k0 + gch * 8, As + off * 8);
    }
#pragma unroll
    for (int i = 0; i < 4; i++) {
      int off = i * 256 + t;
      int row = off >> 3, ch = off & 7;
      int gch = ch ^ (row & 7);
      GLOAD_LDS(Brow + (size_t)row * 1024 + k0 + gch * 8, Bs + off * 8);
    }
    __syncthreads();
#pragma unroll
    for (int kh = 0; kh < 2; kh++) {
      bf16x8 af[4], bfr[4];
#pragma unroll
      for (int i = 0; i < 4; i++) {
        int row = wy * 64 + i * 16 + lr;
        int c = kh * 4 + lg;
        af[i] = *(const bf16x8*)(As + row * 64 + ((c ^ (row & 7)) << 3));
      }
#pragma unroll
      for (int j = 0; j < 4; j++) {
        int row = wx * 64 + j * 16 + lr;
        int c = kh * 4 + lg;
        bfr[j] = *(const bf16x8*)(Bs + row * 64 + ((c ^ (row & 7)) << 3));
      }
#pragma unroll
      for (int i = 0; i < 4; i++)
#pragma unroll
        for (int j = 0; j < 4; j++)
          acc[i][j] = MFMA16(af[i], bfr[j], acc[i][j]);
    }
  }

  const int seg = bn >> 3;
  const float* bias = (seg == 0) ? b0 : (seg == 1 ? b1 : b2);
  const float bscale = (seg == 0) ? QSCALE : 1.0f;

#pragma unroll
  for (int i = 0; i < 4; i++) {
    const int rowb = bm * 128 + wy * 64 + i * 16 + lg * 4;
#pragma unroll
    for (int j = 0; j < 4; j++) {
      const int np = bn * 128 + wx * 64 + j * 16 + lr;
      const int col = np & 1023;
      const float bv = bias[col] * bscale;
      const int h = col >> 6, d = col & 63;
      const int bb = rowb >> 11, nn = rowb & 2047;
      if (seg == 2) {  // V^T
        bf16x4 pk;
#pragma unroll
        for (int r = 0; r < 4; r++) pk[r] = (bf16)(acc[i][j][r] + bv);
        *(bf16x4*)(o2 + (((size_t)bb * 16 + h) * 64 + d) * 2048 + nn) = pk;
      } else {
        bf16* dst = (seg == 0) ? o0 : o1;
#pragma unroll
        for (int r = 0; r < 4; r++)
          dst[(((size_t)bb * 16 + h) * 2048 + nn + r) * 64 + d] =
              (bf16)(acc[i][j][r] + bv);
      }
    }
  }
}

// ---------------- out-projection GEMM: 128x64 tiles, grid 512 -----------------
__global__ __launch_bounds__(256, 2) void gemmo_kernel(
    const bf16* __restrict__ A, const bf16* __restrict__ Bt,
    const float* __restrict__ bias, float* __restrict__ out) {
  __shared__ bf16 As[128 * 64];
  __shared__ bf16 Bs[64 * 64];
  const int f = blockIdx.y * 16 + blockIdx.x;
  const int wg = (f & 7) * 64 + (f >> 3);
  const int bn = wg & 15, bm = wg >> 4;
  const int t = threadIdx.x;
  const int lane = t & 63, wid = t >> 6;
  const int wy = wid >> 1, wx = wid & 1;
  const int lr = lane & 15, lg = lane >> 4;
  const bf16* Arow = A + (size_t)bm * 128 * 1024;
  const bf16* Brow = Bt + (size_t)bn * 64 * 1024;
  f32x4 acc[4][2] = {};

  for (int k0 = 0; k0 < 1024; k0 += 64) {
    __syncthreads();
#pragma unroll
    for (int i = 0; i < 4; i++) {
      int off = i * 256 + t;
      int row = off >> 3, ch = off & 7;
      int gch = ch ^ (row & 7);
      GLOAD_LDS(Arow + (size_t)row * 1024 + k0 + gch * 8, As + off * 8);
    }
#pragma unroll
    for (int i = 0; i < 2; i++) {
      int off = i * 256 + t;
      int row = off >> 3, ch = off & 7;
      int gch = ch ^ (row & 7);
      GLOAD_LDS(Brow + (size_t)row * 1024 + k0 + gch * 8, Bs + off * 8);
    }
    __syncthreads();
#pragma unroll
    for (int kh = 0; kh < 2; kh++) {
      bf16x8 af[4], bfr[2];
#pragma unroll
      for (int i = 0; i < 4; i++) {
        int row = wy * 64 + i * 16 + lr;
        int c = kh * 4 + lg;
        af[i] = *(const bf16x8*)(As + row * 64 + ((c ^ (row & 7)) << 3));
      }
#pragma unroll
      for (int j = 0; j < 2; j++) {
        int row = wx * 32 + j * 16 + lr;
        int c = kh * 4 + lg;
        bfr[j] = *(const bf16x8*)(Bs + row * 64 + ((c ^ (row & 7)) << 3));
      }
#pragma unroll
      for (int i = 0; i < 4; i++)
#pragma unroll
        for (int j = 0; j < 2; j++)
          acc[i][j] = MFMA16(af[i], bfr[j], acc[i][j]);
    }
  }

#pragma unroll
  for (int i = 0; i < 4; i++) {
    const int rowb = bm * 128 + wy * 64 + i * 16 + lg * 4;
#pragma unroll
    for (int j = 0; j < 2; j++) {
      const int col = bn * 64 + wx * 32 + j * 16 + lr;
      const float bv = bias[col];
#pragma unroll
      for (int r = 0; r < 4; r++)
        out[(size_t)(rowb + r) * 1024 + col] = acc[i][j][r] + bv;
    }
  }
}

// ---------------- Flash attention: T15 two-tile pipeline, key-split -----------
// grid (32,32) remapped: xcd = f&7 -> bh = xcd*4 + slot/32 (K/V XCD-L2-resident).
// 256 threads = 4 waves; 2 waves per key-half. Per iter kt: PRELOAD tile kt+1
// (QK MFMA into fresh S-set + V fragments into REGISTERS from LDS), then
// CONSUME tile kt (exp+pack VALU — independent of the in-flight QK MFMAs, so
// the pipes overlap — then PV from the registers loaded last iter), then stage
// kt+2, barrier. Static A/B register sets (unroll-2). osum denominator on the
// MFMA pipe; no-max exp2 softmax (halves additive); LDS merge at end.
__global__ __launch_bounds__(256, 2) void attn_kernel(
    const bf16* __restrict__ Q, const bf16* __restrict__ K,
    const bf16* __restrict__ Vt, bf16* __restrict__ Mg) {
  __shared__ bf16 Kl[2][2][4096];  // [half][buf][64 key * 64 d]
  __shared__ bf16 Vl[2][2][4096];  // [half][buf][64 d * 64 key]
  const int t = threadIdx.x;
  const int lane = t & 63, w = t >> 6;   // 4 waves
  const int half = w >> 1, wq = w & 1;
  const int l31 = lane & 31, hi = lane >> 5;
  const int f = blockIdx.y * 32 + blockIdx.x;  // 1024 blocks, 1024%8==0
  const int xcd = f & 7, slot = f >> 3;        // slot 0..127
  const int bh = xcd * 4 + (slot >> 5);
  const int bx = slot & 31;
  const int b = bh >> 4, h = bh & 15;
  const bf16* Qh = Q + (size_t)bh * 2048 * 64;
  const bf16* KhH = K + (size_t)bh * 2048 * 64 + (size_t)half * 1024 * 64;
  const bf16* VhH = Vt + (size_t)bh * 64 * 2048 + half * 1024;
  const int q_row = bx * 64 + wq * 32 + l31;
  const int r0 = l31, r1 = 32 + l31;

  bf16x8 qf[4];
#pragma unroll
  for (int dblk = 0; dblk < 4; dblk++)
    qf[dblk] = *(const bf16x8*)(Qh + (size_t)q_row * 64 + dblk * 16 + hi * 8);

  bf16x8 onesA;
  {
    bf16 ov = (l31 == 0) ? (bf16)1.0f : (bf16)0.0f;
#pragma unroll
    for (int e = 0; e < 8; e++) onesA[e] = ov;
  }

  f32x16 o0 = {}, o1 = {}, osum = {};
  const int th = t & 127;  // half-local thread id (128 threads per half)

  // stage tile kt_ of this half into buf_: K 512 chunks + V 512 chunks
#define STAGE_KV(kt_, buf_)                                                   \
  {                                                                           \
    _Pragma("unroll") for (int i = 0; i < 4; i++) {                           \
      int off = i * 128 + th;                                                 \
      int row = off >> 3, ch = off & 7;                                       \
      int gch = ch ^ (row & 7);                                               \
      GLOAD_LDS(KhH + (size_t)(kt_) * 4096 + row * 64 + gch * 8,              \
                &Kl[half][buf_][off * 8]);                                    \
      GLOAD_LDS(VhH + (size_t)row * 2048 + (kt_) * 64 + gch * 8,              \
                &Vl[half][buf_][off * 8]);                                    \
    }                                                                         \
  }

  // QK MFMA into fresh S set + V fragments LDS->reg, all from buf_
#define PRELOAD(buf_, s0_, s1_, v0_, v1_)                                     \
  {                                                                           \
    s0_ = (f32x16){};                                                         \
    s1_ = (f32x16){};                                                         \
    __builtin_amdgcn_s_setprio(1);                                            \
    _Pragma("unroll") for (int dblk = 0; dblk < 4; dblk++) {                  \
      const int c = dblk * 2 + hi;                                            \
      bf16x8 kf0 =                                                            \
          *(const bf16x8*)&Kl[half][buf_][r0 * 64 + ((c ^ (r0 & 7)) << 3)];   \
      bf16x8 kf1 =                                                            \
          *(const bf16x8*)&Kl[half][buf_][r1 * 64 + ((c ^ (r1 & 7)) << 3)];   \
      s0_ = MFMA32(kf0, qf[dblk], s0_);                                       \
      s1_ = MFMA32(kf1, qf[dblk], s1_);                                       \
    }                                                                         \
    __builtin_amdgcn_s_setprio(0);                                            \
    _Pragma("unroll") for (int kbl = 0; kbl < 4; kbl++) {                     \
      const int c = kbl * 2 + hi;                                             \
      v0_[kbl] =                                                              \
          *(const bf16x8*)&Vl[half][buf_][r0 * 64 + ((c ^ (r0 & 7)) << 3)];   \
      v1_[kbl] =                                                              \
          *(const bf16x8*)&Vl[half][buf_][r1 * 64 + ((c ^ (r1 & 7)) << 3)];   \
    }                                                                         \
  }

  // exp+pack S set, then PV from the register-held V fragments
#define CONSUME(s0_, s1_, v0_, v1_)                                           \
  {                                                                           \
    _Pragma("unroll") for (int r = 0; r < 16; r++) {                          \
      s0_[r] = __builtin_amdgcn_exp2f(s0_[r]);                                \
      s1_[r] = __builtin_amdgcn_exp2f(s1_[r]);                                \
    }                                                                         \
    uint prc[8], prd[8];                                                      \
    _Pragma("unroll") for (int si = 0; si < 4; si++) {                        \
      prc[si] = pack2(s0_[4 * si + 0], s0_[4 * si + 1]);                      \
      prd[si] = pack2(s0_[4 * si + 2], s0_[4 * si + 3]);                      \
      prc[4 + si] = pack2(s1_[4 * si + 0], s1_[4 * si + 1]);                  \
      prd[4 + si] = pack2(s1_[4 * si + 2], s1_[4 * si + 3]);                  \
    }                                                                         \
    __builtin_amdgcn_s_setprio(1);                                            \
    _Pragma("unroll") for (int kbl = 0; kbl < 4; kbl++) {                     \
      const int sb = (kbl >> 1) * 4 + (kbl & 1) * 2;                          \
      auto rc =                                                               \
          __builtin_amdgcn_permlane32_swap(prc[sb], prc[sb + 1], false, false);\
      auto rd =                                                               \
          __builtin_amdgcn_permlane32_swap(prd[sb], prd[sb + 1], false, false);\
      union { uint u[4]; bf16x8 v; } pf;                                      \
      pf.u[0] = rc[0];                                                        \
      pf.u[1] = rd[0];                                                        \
      pf.u[2] = rc[1];                                                        \
      pf.u[3] = rd[1];                                                        \
      o0 = MFMA32(v0_[kbl], pf.v, o0);                                        \
      o1 = MFMA32(v1_[kbl], pf.v, o1);                                        \
      osum = MFMA32(onesA, pf.v, osum);                                       \
    }                                                                         \
    __builtin_amdgcn_s_setprio(0);                                            \
  }

  // pipeline state: two named register sets (rule #20: static indexing only)
  f32x16 sa0, sa1, sb0, sb1;
  bf16x8 va0[4], va1[4], vb0[4], vb1[4];

  // prologue: tile 0 staged+loaded; tile 1 staged
  STAGE_KV(0, 0);
  __syncthreads();
  PRELOAD(0, sa0, sa1, va0, va1);  // tile 0 -> set A
  STAGE_KV(1, 1);
  __syncthreads();

  // main loop, unroll-2 for the A/B rename
#pragma unroll 1
  for (int kt2 = 0; kt2 < 16; kt2 += 2) {
    {  // iter kt = kt2 (even): consume A, preload B (tile kt+1 in buf 1)
      const int kt = kt2;
      if (kt < 15) PRELOAD((kt + 1) & 1, sb0, sb1, vb0, vb1);
      if (kt < 14) STAGE_KV(kt + 2, kt & 1);
      CONSUME(sa0, sa1, va0, va1);
      __syncthreads();
    }
    {  // iter kt = kt2+1 (odd): consume B, preload A
      const int kt = kt2 + 1;
      if (kt < 15) PRELOAD((kt + 1) & 1, sa0, sa1, va0, va1);
      if (kt < 14) STAGE_KV(kt + 2, kt & 1);
      CONSUME(sb0, sb1, vb0, vb1);
      __syncthreads();
    }
  }

  // ---- denominator (osum row 0) broadcast, R6-verified pattern ----
  uint lu = __builtin_bit_cast(uint, osum[0]);
  auto lb = __builtin_amdgcn_permlane32_swap(lu, lu, false, false);
  const float den = __builtin_bit_cast(float, (uint)lb[0]);

  // ---- merge halves via LDS; stride-17 float rows (conflict-free) ----
  float* ma = (float*)&Kl[0][0][0];  // 128 rows * 17 * 4 B
  float* mb = (float*)&Vl[0][0][0];
  const int mi = (wq * 64 + lane) * 17;
  if (half == 1) {
#pragma unroll
    for (int si = 0; si < 16; si++) {
      ma[mi + si] = o0[si];
      mb[mi + si] = o1[si];
    }
    ma[mi + 16] = den;
  }
  __syncthreads();
  if (half == 0) {
    const float inv = 1.f / (den + ma[mi + 16]);
    bf16* orow = Mg + ((size_t)b * 2048 + q_row) * 1024 + h * 64;
#pragma unroll
    for (int si = 0; si < 4; si++) {
      bf16x4 p0, p1;
#pragma unroll
      for (int r = 0; r < 4; r++) {
        p0[r] = (bf16)((o0[4 * si + r] + ma[mi + 4 * si + r]) * inv);
        p1[r] = (bf16)((o1[4 * si + r] + mb[mi + 4 * si + r]) * inv);
      }
      *(bf16x4*)(orow + si * 8 + hi * 4) = p0;
      *(bf16x4*)(orow + 32 + si * 8 + hi * 4) = p1;
    }
  }
}

// ---------------- launch ----------------
extern "C" void kernel_launch(void* const* d_in, const int* in_sizes, int n_in,
                              void* d_out, int out_size, void* d_ws, size_t ws_size,
                              hipStream_t stream) {
  const float* x  = (const float*)d_in[0];
  const float* Wq = (const float*)d_in[1];
  const float* bq = (const float*)d_in[2];
  const float* Wk = (const float*)d_in[3];
  const float* bk = (const float*)d_in[4];
  const float* Wv = (const float*)d_in[5];
  const float* bv = (const float*)d_in[6];
  const float* Wo = (const float*)d_in[7];
  const float* bo = (const float*)d_in[8];
  float* out = (float*)d_out;
  char* ws = (char*)d_ws;
  const size_t MiB = 1u << 20;

  bf16* Xb   = (bf16*)(ws);             // 8 MiB; reused as merged heads
  bf16* Mg   = Xb;
  bf16* Wqkv = (bf16*)(ws + 8 * MiB);   // 6 MiB: [3072][1024]
  bf16* WoT  = (bf16*)(ws + 14 * MiB);  // 2 MiB
  bf16* Qb   = (bf16*)(ws + 16 * MiB);  // [B][H][N][64]
  bf16* Kb   = (bf16*)(ws + 24 * MiB);  // [B][H][N][64]
  bf16* Vtb  = (bf16*)(ws + 32 * MiB);  // [B][H][64][N]

  prep_kernel<<<6144, 256, 0, stream>>>(
      x, Xb, Wq, Wk, Wv, Wo, Wqkv, Wqkv + (1u << 20), Wqkv + (2u << 20), WoT);
  gemm_qkv_kernel<<<dim3(24, 32), 256, 0, stream>>>(
      Xb, Wqkv, bq, bk, bv, Qb, Kb, Vtb);
  attn_kernel<<<dim3(32, 32), 256, 0, stream>>>(Qb, Kb, Vtb, Mg);
  gemmo_kernel<<<dim3(16, 32), 256, 0, stream>>>(Mg, WoT, bo, out);
  (void)in_sizes; (void)n_in; (void)out_size; (void)ws_size;
}

// Round 13
// 109.843 us; speedup vs baseline: 1.1535x; 1.1535x over previous
//
#include <hip/hip_runtime.h>
#include <hip/hip_bf16.h>

typedef __bf16 bf16;
typedef __attribute__((ext_vector_type(8))) __bf16 bf16x8;
typedef __attribute__((ext_vector_type(4))) __bf16 bf16x4;
typedef __attribute__((ext_vector_type(4))) float f32x4;
typedef __attribute__((ext_vector_type(16))) float f32x16;
typedef unsigned int uint;

#define MFMA16(a, b, c) __builtin_amdgcn_mfma_f32_16x16x32_bf16(a, b, c, 0, 0, 0)
#define MFMA32(a, b, c) __builtin_amdgcn_mfma_f32_32x32x16_bf16(a, b, c, 0, 0, 0)

#define GLOAD_LDS(gp, lp) \
  __builtin_amdgcn_global_load_lds( \
      (const __attribute__((address_space(1))) void*)(gp), \
      (__attribute__((address_space(3))) void*)(lp), 16, 0, 0)

#define QSCALE 0.18033688011112042f  /* 0.125 * log2(e) */

__device__ __forceinline__ uint pack2(float a, float b) {
  unsigned short x = __builtin_bit_cast(unsigned short, (bf16)a);
  unsigned short y = __builtin_bit_cast(unsigned short, (bf16)b);
  return (uint)x | ((uint)y << 16);
}

// ---------------- prep: x cvt (blocks 0..2047) + 4 weight transposes ----------
__global__ __launch_bounds__(256) void prep_kernel(
    const float* __restrict__ x, bf16* __restrict__ y,
    const float* __restrict__ W0, const float* __restrict__ W1,
    const float* __restrict__ W2, const float* __restrict__ W3,
    bf16* __restrict__ T0, bf16* __restrict__ T1,
    bf16* __restrict__ T2, bf16* __restrict__ T3) {
  const int bid = blockIdx.x;
  if (bid < 2048) {
    int i = (bid * 256 + threadIdx.x) * 8;
    float4 a = *(const float4*)(x + i);
    float4 b = *(const float4*)(x + i + 4);
    bf16x8 v;
    v[0] = (bf16)a.x; v[1] = (bf16)a.y; v[2] = (bf16)a.z; v[3] = (bf16)a.w;
    v[4] = (bf16)b.x; v[5] = (bf16)b.y; v[6] = (bf16)b.z; v[7] = (bf16)b.w;
    *(bf16x8*)(y + i) = v;
    return;
  }
  const int wq = bid - 2048;
  const int z = wq >> 10, rem = wq & 1023;
  const float* W; bf16* T;
  switch (z) {
    case 0: W = W0; T = T0; break;
    case 1: W = W1; T = T1; break;
    case 2: W = W2; T = T2; break;
    default: W = W3; T = T3; break;
  }
  const float scl = (z == 0) ? QSCALE : 1.0f;
  __shared__ float tile[32][33];
  int tx = threadIdx.x & 31;
  int ty = threadIdx.x >> 5;
  int bx = (rem & 31) * 32, by = (rem >> 5) * 32;
#pragma unroll
  for (int i = 0; i < 32; i += 8)
    tile[ty + i][tx] = W[(size_t)(by + ty + i) * 1024 + bx + tx];
  __syncthreads();
#pragma unroll
  for (int i = 0; i < 32; i += 8)
    T[(size_t)(bx + ty + i) * 1024 + by + tx] = (bf16)(tile[tx][ty + i] * scl);
}

// ---------------- fused QKV GEMM: [4096][1024] x [3072][1024]^T ----------------
__global__ __launch_bounds__(256, 2) void gemm_qkv_kernel(
    const bf16* __restrict__ A, const bf16* __restrict__ Bt,
    const float* __restrict__ b0, const float* __restrict__ b1,
    const float* __restrict__ b2, bf16* __restrict__ o0,
    bf16* __restrict__ o1, bf16* __restrict__ o2) {
  __shared__ bf16 As[128 * 64];
  __shared__ bf16 Bs[128 * 64];
  const int f = blockIdx.y * 24 + blockIdx.x;
  const int wg = (f % 8) * 96 + f / 8;
  const int bn = wg % 24, bm = wg / 24;
  const int t = threadIdx.x;
  const int lane = t & 63, wid = t >> 6;
  const int wy = wid >> 1, wx = wid & 1;
  const int lr = lane & 15, lg = lane >> 4;
  const bf16* Arow = A + (size_t)bm * 128 * 1024;
  const bf16* Brow = Bt + (size_t)bn * 128 * 1024;
  f32x4 acc[4][4] = {};

  for (int k0 = 0; k0 < 1024; k0 += 64) {
    __syncthreads();
#pragma unroll
    for (int i = 0; i < 4; i++) {
      int off = i * 256 + t;
      int row = off >> 3, ch = off & 7;
      int gch = ch ^ (row & 7);
      GLOAD_LDS(Arow + (size_t)row * 1024 + k0 + gch * 8, As + off * 8);
    }
#pragma unroll
    for (int i = 0; i < 4; i++) {
      int off = i * 256 + t;
      int row = off >> 3, ch = off & 7;
      int gch = ch ^ (row & 7);
      GLOAD_LDS(Brow + (size_t)row * 1024 + k0 + gch * 8, Bs + off * 8);
    }
    __syncthreads();
#pragma unroll
    for (int kh = 0; kh < 2; kh++) {
      bf16x8 af[4], bfr[4];
#pragma unroll
      for (int i = 0; i < 4; i++) {
        int row = wy * 64 + i * 16 + lr;
        int c = kh * 4 + lg;
        af[i] = *(const bf16x8*)(As + row * 64 + ((c ^ (row & 7)) << 3));
      }
#pragma unroll
      for (int j = 0; j < 4; j++) {
        int row = wx * 64 + j * 16 + lr;
        int c = kh * 4 + lg;
        bfr[j] = *(const bf16x8*)(Bs + row * 64 + ((c ^ (row & 7)) << 3));
      }
#pragma unroll
      for (int i = 0; i < 4; i++)
#pragma unroll
        for (int j = 0; j < 4; j++)
          acc[i][j] = MFMA16(af[i], bfr[j], acc[i][j]);
    }
  }

  const int seg = bn >> 3;
  const float* bias = (seg == 0) ? b0 : (seg == 1 ? b1 : b2);
  const float bscale = (seg == 0) ? QSCALE : 1.0f;

#pragma unroll
  for (int i = 0; i < 4; i++) {
    const int rowb = bm * 128 + wy * 64 + i * 16 + lg * 4;
#pragma unroll
    for (int j = 0; j < 4; j++) {
      const int np = bn * 128 + wx * 64 + j * 16 + lr;
      const int col = np & 1023;
      const float bv = bias[col] * bscale;
      const int h = col >> 6, d = col & 63;
      const int bb = rowb >> 11, nn = rowb & 2047;
      if (seg == 2) {  // V^T
        bf16x4 pk;
#pragma unroll
        for (int r = 0; r < 4; r++) pk[r] = (bf16)(acc[i][j][r] + bv);
        *(bf16x4*)(o2 + (((size_t)bb * 16 + h) * 64 + d) * 2048 + nn) = pk;
      } else {
        bf16* dst = (seg == 0) ? o0 : o1;
#pragma unroll
        for (int r = 0; r < 4; r++)
          dst[(((size_t)bb * 16 + h) * 2048 + nn + r) * 64 + d] =
              (bf16)(acc[i][j][r] + bv);
      }
    }
  }
}

// ---------------- out-projection GEMM: 128x64 tiles, grid 512 -----------------
__global__ __launch_bounds__(256, 2) void gemmo_kernel(
    const bf16* __restrict__ A, const bf16* __restrict__ Bt,
    const float* __restrict__ bias, float* __restrict__ out) {
  __shared__ bf16 As[128 * 64];
  __shared__ bf16 Bs[64 * 64];
  const int f = blockIdx.y * 16 + blockIdx.x;
  const int wg = (f & 7) * 64 + (f >> 3);
  const int bn = wg & 15, bm = wg >> 4;
  const int t = threadIdx.x;
  const int lane = t & 63, wid = t >> 6;
  const int wy = wid >> 1, wx = wid & 1;
  const int lr = lane & 15, lg = lane >> 4;
  const bf16* Arow = A + (size_t)bm * 128 * 1024;
  const bf16* Brow = Bt + (size_t)bn * 64 * 1024;
  f32x4 acc[4][2] = {};

  for (int k0 = 0; k0 < 1024; k0 += 64) {
    __syncthreads();
#pragma unroll
    for (int i = 0; i < 4; i++) {
      int off = i * 256 + t;
      int row = off >> 3, ch = off & 7;
      int gch = ch ^ (row & 7);
      GLOAD_LDS(Arow + (size_t)row * 1024 + k0 + gch * 8, As + off * 8);
    }
#pragma unroll
    for (int i = 0; i < 2; i++) {
      int off = i * 256 + t;
      int row = off >> 3, ch = off & 7;
      int gch = ch ^ (row & 7);
      GLOAD_LDS(Brow + (size_t)row * 1024 + k0 + gch * 8, Bs + off * 8);
    }
    __syncthreads();
#pragma unroll
    for (int kh = 0; kh < 2; kh++) {
      bf16x8 af[4], bfr[2];
#pragma unroll
      for (int i = 0; i < 4; i++) {
        int row = wy * 64 + i * 16 + lr;
        int c = kh * 4 + lg;
        af[i] = *(const bf16x8*)(As + row * 64 + ((c ^ (row & 7)) << 3));
      }
#pragma unroll
      for (int j = 0; j < 2; j++) {
        int row = wx * 32 + j * 16 + lr;
        int c = kh * 4 + lg;
        bfr[j] = *(const bf16x8*)(Bs + row * 64 + ((c ^ (row & 7)) << 3));
      }
#pragma unroll
      for (int i = 0; i < 4; i++)
#pragma unroll
        for (int j = 0; j < 2; j++)
          acc[i][j] = MFMA16(af[i], bfr[j], acc[i][j]);
    }
  }

#pragma unroll
  for (int i = 0; i < 4; i++) {
    const int rowb = bm * 128 + wy * 64 + i * 16 + lg * 4;
#pragma unroll
    for (int j = 0; j < 2; j++) {
      const int col = bn * 64 + wx * 32 + j * 16 + lr;
      const float bv = bias[col];
#pragma unroll
      for (int r = 0; r < 4; r++)
        out[(size_t)(rowb + r) * 1024 + col] = acc[i][j][r] + bv;
    }
  }
}

// ---------------- Flash attention: R6-exact (in-block key-split, 8 waves) -----
__global__ __launch_bounds__(512, 4) void attn_kernel(
    const bf16* __restrict__ Q, const bf16* __restrict__ K,
    const bf16* __restrict__ Vt, bf16* __restrict__ Mg) {
  __shared__ bf16 Kl[2][2][4096];  // [half][buf][64*64]
  __shared__ bf16 Vl[2][2][4096];
  const int t = threadIdx.x;
  const int lane = t & 63, w = t >> 6;
  const int half = w >> 2, wq = w & 3;
  const int l31 = lane & 31, hi = lane >> 5;
  const int f = blockIdx.y * 16 + blockIdx.x;
  const int xcd = f & 7, slot = f >> 3;
  const int bh = xcd * 4 + (slot >> 4);
  const int bx = slot & 15;
  const int b = bh >> 4, h = bh & 15;
  const bf16* Qh = Q + (size_t)bh * 2048 * 64;
  const bf16* KhH = K + (size_t)bh * 2048 * 64 + (size_t)half * 1024 * 64;
  const bf16* VhH = Vt + (size_t)bh * 64 * 2048 + half * 1024;
  const int q_row = bx * 128 + wq * 32 + l31;

  bf16x8 qf[4];
#pragma unroll
  for (int dblk = 0; dblk < 4; dblk++)
    qf[dblk] = *(const bf16x8*)(Qh + (size_t)q_row * 64 + dblk * 16 + hi * 8);

  bf16x8 onesA;
  {
    bf16 ov = (l31 == 0) ? (bf16)1.0f : (bf16)0.0f;
#pragma unroll
    for (int e = 0; e < 8; e++) onesA[e] = ov;
  }

  f32x16 o0 = {}, o1 = {}, osum = {};
  const int th = t & 255;

#define STAGE_KV(kt_, buf_)                                                   \
  {                                                                           \
    _Pragma("unroll") for (int i = 0; i < 2; i++) {                           \
      int off = i * 256 + th;                                                 \
      int row = off >> 3, ch = off & 7;                                       \
      int gch = ch ^ (row & 7);                                               \
      GLOAD_LDS(KhH + (size_t)(kt_) * 4096 + row * 64 + gch * 8,              \
                &Kl[half][buf_][off * 8]);                                    \
      GLOAD_LDS(VhH + (size_t)row * 2048 + (kt_) * 64 + gch * 8,              \
                &Vl[half][buf_][off * 8]);                                    \
    }                                                                         \
  }

  STAGE_KV(0, 0);
  __syncthreads();

  for (int kt = 0; kt < 16; kt++) {
    const int cur = kt & 1;
    if (kt < 15) STAGE_KV(kt + 1, cur ^ 1);

    f32x16 s0 = {}, s1 = {};
    __builtin_amdgcn_s_setprio(1);
#pragma unroll
    for (int dblk = 0; dblk < 4; dblk++) {
      const int c = dblk * 2 + hi;
      const int r0 = l31, r1 = 32 + l31;
      bf16x8 kf0 = *(const bf16x8*)&Kl[half][cur][r0 * 64 + ((c ^ (r0 & 7)) << 3)];
      bf16x8 kf1 = *(const bf16x8*)&Kl[half][cur][r1 * 64 + ((c ^ (r1 & 7)) << 3)];
      s0 = MFMA32(kf0, qf[dblk], s0);
      s1 = MFMA32(kf1, qf[dblk], s1);
    }
    __builtin_amdgcn_s_setprio(0);

#pragma unroll
    for (int r = 0; r < 16; r++) {
      s0[r] = __builtin_amdgcn_exp2f(s0[r]);
      s1[r] = __builtin_amdgcn_exp2f(s1[r]);
    }

    uint prc[8], prd[8];
#pragma unroll
    for (int si = 0; si < 4; si++) {
      prc[si] = pack2(s0[4 * si + 0], s0[4 * si + 1]);
      prd[si] = pack2(s0[4 * si + 2], s0[4 * si + 3]);
      prc[4 + si] = pack2(s1[4 * si + 0], s1[4 * si + 1]);
      prd[4 + si] = pack2(s1[4 * si + 2], s1[4 * si + 3]);
    }

    __builtin_amdgcn_s_setprio(1);
#pragma unroll
    for (int kbl = 0; kbl < 4; kbl++) {
      const int sb = (kbl >> 1) * 4 + (kbl & 1) * 2;
      auto rc = __builtin_amdgcn_permlane32_swap(prc[sb], prc[sb + 1], false, false);
      auto rd = __builtin_amdgcn_permlane32_swap(prd[sb], prd[sb + 1], false, false);
      union { uint u[4]; bf16x8 v; } pf;
      pf.u[0] = rc[0];
      pf.u[1] = rd[0];
      pf.u[2] = rc[1];
      pf.u[3] = rd[1];

      const int c = kbl * 2 + hi;
      const int r0 = l31, r1 = 32 + l31;
      bf16x8 vt0 = *(const bf16x8*)&Vl[half][cur][r0 * 64 + ((c ^ (r0 & 7)) << 3)];
      bf16x8 vt1 = *(const bf16x8*)&Vl[half][cur][r1 * 64 + ((c ^ (r1 & 7)) << 3)];
      o0 = MFMA32(vt0, pf.v, o0);
      o1 = MFMA32(vt1, pf.v, o1);
      osum = MFMA32(onesA, pf.v, osum);
    }
    __builtin_amdgcn_s_setprio(0);

    __syncthreads();
  }

  uint lu = __builtin_bit_cast(uint, osum[0]);
  auto lb = __builtin_amdgcn_permlane32_swap(lu, lu, false, false);
  const float den = __builtin_bit_cast(float, (uint)lb[0]);

  float* ma = (float*)&Kl[0][0][0];
  float* mb = (float*)&Vl[0][0][0];
  const int mi = (wq * 64 + lane) * 17;
  if (half == 1) {
#pragma unroll
    for (int si = 0; si < 16; si++) {
      ma[mi + si] = o0[si];
      mb[mi + si] = o1[si];
    }
    ma[mi + 16] = den;
  }
  __syncthreads();
  if (half == 0) {
    const float inv = 1.f / (den + ma[mi + 16]);
    bf16* orow = Mg + ((size_t)b * 2048 + q_row) * 1024 + h * 64;
#pragma unroll
    for (int si = 0; si < 4; si++) {
      bf16x4 p0, p1;
#pragma unroll
      for (int r = 0; r < 4; r++) {
        p0[r] = (bf16)((o0[4 * si + r] + ma[mi + 4 * si + r]) * inv);
        p1[r] = (bf16)((o1[4 * si + r] + mb[mi + 4 * si + r]) * inv);
      }
      *(bf16x4*)(orow + si * 8 + hi * 4) = p0;
      *(bf16x4*)(orow + 32 + si * 8 + hi * 4) = p1;
    }
  }
}

// ---------------- launch ----------------
extern "C" void kernel_launch(void* const* d_in, const int* in_sizes, int n_in,
                              void* d_out, int out_size, void* d_ws, size_t ws_size,
                              hipStream_t stream) {
  const float* x  = (const float*)d_in[0];
  const float* Wq = (const float*)d_in[1];
  const float* bq = (const float*)d_in[2];
  const float* Wk = (const float*)d_in[3];
  const float* bk = (const float*)d_in[4];
  const float* Wv = (const float*)d_in[5];
  const float* bv = (const float*)d_in[6];
  const float* Wo = (const float*)d_in[7];
  const float* bo = (const float*)d_in[8];
  float* out = (float*)d_out;
  char* ws = (char*)d_ws;
  const size_t MiB = 1u << 20;

  bf16* Xb   = (bf16*)(ws);             // 8 MiB; reused as merged heads
  bf16* Mg   = Xb;
  bf16* Wqkv = (bf16*)(ws + 8 * MiB);   // 6 MiB: [3072][1024]
  bf16* WoT  = (bf16*)(ws + 14 * MiB);  // 2 MiB
  bf16* Qb   = (bf16*)(ws + 16 * MiB);  // [B][H][N][64]
  bf16* Kb   = (bf16*)(ws + 24 * MiB);  // [B][H][N][64]
  bf16* Vtb  = (bf16*)(ws + 32 * MiB);  // [B][H][64][N]

  prep_kernel<<<6144, 256, 0, stream>>>(
      x, Xb, Wq, Wk, Wv, Wo, Wqkv, Wqkv + (1u << 20), Wqkv + (2u << 20), WoT);
  gemm_qkv_kernel<<<dim3(24, 32), 256, 0, stream>>>(
      Xb, Wqkv, bq, bk, bv, Qb, Kb, Vtb);
  attn_kernel<<<dim3(16, 32), 512, 0, stream>>>(Qb, Kb, Vtb, Mg);
  gemmo_kernel<<<dim3(16, 32), 256, 0, stream>>>(Mg, WoT, bo, out);
  (void)in_sizes; (void)n_in; (void)out_size; (void)ws_size;
}